// Round 6
// baseline (234.934 us; speedup 1.0000x reference)
//
#include <hip/hip_runtime.h>
#include <math.h>

#define BB 8
#define TT 100
#define PP 1000
#define NJ 52      // V regs per thread in k4 (50 real j, 2 pad)
#define GROW 56    // G row stride floats (224B, 16B aligned)

// mid dynamic LDS (floats): xk_lds [100][256] | h_all [100][64] | w1s [64][52]
#define MID_XK   0
#define MID_HALL 25600
#define MID_W1S  32000
#define MID_SMEM_FLOATS 35328
#define MID_SMEM_BYTES  (MID_SMEM_FLOATS * 4)   // 141312 B <= 160 KiB/CU

typedef _Float16 half2v __attribute__((ext_vector_type(2)));

// ws layout (floats):
//   xk : [800][256] at 0        (204800)
//   XcT: [56][1000] at 204800   (56000)
//   G  : [800][56]  at 260800   (44800)

// ---------------- K1: xk[bt][j] = bias[j] + sum_k xt[bt][k]*kern[k][j] -----------------
__global__ __launch_bounds__(256) void k1_xk(const int* __restrict__ pro_id,
    const int* __restrict__ label, const float* __restrict__ X,
    const float* __restrict__ onehot, const float* __restrict__ kern,
    const float* __restrict__ bias, float* __restrict__ xk)
{
    __shared__ __align__(16) float xt[2][256];
    const int j = threadIdx.x;
    const int r0 = blockIdx.x * 2;
#pragma unroll
    for (int r = 0; r < 2; ++r) {
        int pid = pro_id[r0 + r];
        int lab = label[r0 + r];
        xt[r][j] = X[pid * 128 + (j & 127)] * onehot[lab * 256 + j];
    }
    __syncthreads();
    float acc0 = bias[j], acc1 = acc0;
    float kc[8];
#pragma unroll
    for (int i = 0; i < 8; ++i) kc[i] = kern[i * 256 + j];
    for (int kg = 0; kg < 32; ++kg) {
        float kn[8];
        const int kgn = (kg < 31) ? kg + 1 : 31;
#pragma unroll
        for (int i = 0; i < 8; ++i) kn[i] = kern[(kgn * 8 + i) * 256 + j];
        const int k0 = kg * 8;
        float4 xa0 = *(const float4*)&xt[0][k0];
        float4 xa1 = *(const float4*)&xt[0][k0 + 4];
        float4 xb0 = *(const float4*)&xt[1][k0];
        float4 xb1 = *(const float4*)&xt[1][k0 + 4];
        acc0 += xa0.x * kc[0] + xa0.y * kc[1] + xa0.z * kc[2] + xa0.w * kc[3]
              + xa1.x * kc[4] + xa1.y * kc[5] + xa1.z * kc[6] + xa1.w * kc[7];
        acc1 += xb0.x * kc[0] + xb0.y * kc[1] + xb0.z * kc[2] + xb0.w * kc[3]
              + xb1.x * kc[4] + xb1.y * kc[5] + xb1.z * kc[6] + xb1.w * kc[7];
#pragma unroll
        for (int i = 0; i < 8; ++i) kc[i] = kn[i];
    }
    xk[(r0 + 0) * 256 + j] = acc0;
    xk[(r0 + 1) * 256 + j] = acc1;
}

// ---------------- MID: blocks 0..7 = LSTM (1 batch), blocks 8..23 = XcT (k3) -----------
// LSTM v11: un-poisoned xk-LDS experiment.
// R3/R5 lesson: ANY barrier between rp setup and the loop (even in a divergent
// branch — LLVM tail-merges the two s_barriers and re-splits the scope) makes
// the allocator spill rp (VGPR 140->88, rec reloaded in-loop). So: stage xk+w1s
// with ALL 256 threads, ONE uniform barrier, THEN if(tid<64){rp setup; loop}
// with no barrier inside the rp live range (R2's proven 140-VGPR shape).
// Recurrence touches LDS only: 4 ds_read_b32/step, 2 lanes/bank = conflict-free.
__global__ __launch_bounds__(256, 1) void mid(const float* __restrict__ xk,
    const float* __restrict__ rec, const float* __restrict__ W1,
    const float* __restrict__ X, const float* __restrict__ b1,
    float* __restrict__ G, float* __restrict__ XcT)
{
    extern __shared__ __align__(16) float smem[];
    const int tid = threadIdx.x;

    if (blockIdx.x < 8) {
        float* xk_lds = smem + MID_XK;     // [100][256] f32 = 102400 B
        float* h_all  = smem + MID_HALL;   // [100][64] f32 (for G tail)
        float* w1s    = smem + MID_W1S;    // [64][52]
        const int b = blockIdx.x;

        // ---- ALL threads: stage xk tile (100KB) + w1s, uniform barrier ----
        {
            const float4* xkg = (const float4*)(xk + b * TT * 256);
            float4* xkd = (float4*)xk_lds;
            for (int idx = tid; idx < TT * 64; idx += 256)
                xkd[idx] = xkg[idx];
            for (int idx = tid; idx < 3200; idx += 256) {
                int u2 = idx / 50, jj = idx - u2 * 50;
                w1s[u2 * 52 + jj] = W1[idx];
            }
        }
        __syncthreads();   // uniform: xk_lds + w1s ready

        if (tid < 64) {    // wave 0: rp setup + recurrence, NO barrier in scope
            const int u = tid;
            // rec as f16 dot2 pairs: rp[g][m] = (rec[2m][g*64+u], rec[2m+1][g*64+u])
            half2v rp[4][32];
#pragma unroll
            for (int m = 0; m < 32; ++m) {
#pragma unroll
                for (int g2 = 0; g2 < 4; ++g2) {
                    float r0 = rec[(2 * m) * 256 + g2 * 64 + u];
                    float r1 = rec[(2 * m + 1) * 256 + g2 * 64 + u];
                    half2v pv; pv.x = (_Float16)r0; pv.y = (_Float16)r1;
                    rp[g2][m] = pv;
                }
            }

            float xi = xk_lds[u],       xf = xk_lds[64 + u],
                  xg = xk_lds[128 + u], xo = xk_lds[192 + u];
            float c = 0.f;
            half2v prb; prb.x = (_Float16)0.f; prb.y = (_Float16)0.f;  // h(-1)=0

            for (int t = 0; t < TT; ++t) {
                float zi = xi, zf = xf, zg = xg, zo = xo;
                // prefetch next step's xk row from LDS (hidden under the dots)
                const float* xp = xk_lds + ((t + 1 < TT) ? (t + 1) : (TT - 1)) * 256;
                xi = xp[u];       xf = xp[64 + u];
                xg = xp[128 + u]; xo = xp[192 + u];
                const int prbi = __builtin_bit_cast(int, prb);
#pragma unroll
                for (int m = 0; m < 32; ++m) {
                    half2v pm = __builtin_bit_cast(half2v,
                        __builtin_amdgcn_readlane(prbi, 2 * m));
                    zi = __builtin_amdgcn_fdot2(pm, rp[0][m], zi, false);
                    zf = __builtin_amdgcn_fdot2(pm, rp[1][m], zf, false);
                    zg = __builtin_amdgcn_fdot2(pm, rp[2][m], zg, false);
                    zo = __builtin_amdgcn_fdot2(pm, rp[3][m], zo, false);
                }
                float gi = __builtin_amdgcn_rcpf(1.f + __expf(-zi));
                float gf = __builtin_amdgcn_rcpf(1.f + __expf(-zf));
                float gg = 2.f * __builtin_amdgcn_rcpf(1.f + __expf(-2.f * zg)) - 1.f;
                float go = __builtin_amdgcn_rcpf(1.f + __expf(-zo));
                c = gf * c + gi * gg;
                float h = go * (2.f * __builtin_amdgcn_rcpf(1.f + __expf(-2.f * c)) - 1.f);
                h_all[t * 64 + u] = h;   // f32 history, off critical path
                // (h[u], h[u^1]) via DPP quad_perm [1,0,3,2]
                int hsw = __builtin_amdgcn_update_dpp(0,
                    __builtin_bit_cast(int, h), 0xB1, 0xF, 0xF, true);
                half2v pn;
                pn.x = (_Float16)h;
                pn.y = (_Float16)__builtin_bit_cast(float, hsw);
                prb = pn;   // even lane 2m holds (h[2m], h[2m+1])
            }
        }
        __syncthreads();   // uniform: h_all visible to all 4 waves

        // ---- G tail (all 256 threads): G[b*100+row][j] = h(row) . W1[:,j] ----
        const int brow0 = b * TT;
        for (int idx = tid; idx < TT * 13; idx += 256) {
            int row = idx / 13;
            int m = idx - row * 13;
            int j = 4 * m;
            const float* hrow = &h_all[row * 64];
            float ax = 0.f, ay = 0.f, az = 0.f, aw = 0.f;
#pragma unroll
            for (int u4 = 0; u4 < 16; ++u4) {
                float4 hv  = *(const float4*)&hrow[4 * u4];
                float4 w0  = *(const float4*)&w1s[(4 * u4 + 0) * 52 + j];
                float4 w1v = *(const float4*)&w1s[(4 * u4 + 1) * 52 + j];
                float4 w2  = *(const float4*)&w1s[(4 * u4 + 2) * 52 + j];
                float4 w3  = *(const float4*)&w1s[(4 * u4 + 3) * 52 + j];
                ax += hv.x * w0.x + hv.y * w1v.x + hv.z * w2.x + hv.w * w3.x;
                ay += hv.x * w0.y + hv.y * w1v.y + hv.z * w2.y + hv.w * w3.y;
                az += hv.x * w0.z + hv.y * w1v.z + hv.z * w2.z + hv.w * w3.z;
                aw += hv.x * w0.w + hv.y * w1v.w + hv.z * w2.w + hv.w * w3.w;
            }
            if (m == 12) { az = 0.f; aw = 0.f; }   // cols 50,51 = 0
            *(float4*)&G[(brow0 + row) * GROW + j] = make_float4(ax, ay, az, aw);
        }
    } else {
        // ---- k3: XcT[j][p] = b1[j] + sum_k X[p][k]*W1[64+k][j] ----
        float* Xs  = smem;          // [128][65]
        float* W1T = smem + 8320;   // [50][128]
        const int p0 = (blockIdx.x - 8) * 64;
        for (int idx = tid; idx < 6400; idx += 256) {
            int k = idx & 127, jj = idx >> 7;
            W1T[jj * 128 + k] = W1[(64 + k) * 50 + jj];
        }
#pragma unroll
        for (int r = 0; r < 8; ++r) {
            int flat = (tid + 256 * r) * 4;
            int i = flat >> 7;
            int k = flat & 127;
            int p = p0 + i;
            float4 v = make_float4(0.f, 0.f, 0.f, 0.f);
            if (p < PP) v = *(const float4*)&X[p * 128 + k];
            Xs[(k + 0) * 65 + i] = v.x;
            Xs[(k + 1) * 65 + i] = v.y;
            Xs[(k + 2) * 65 + i] = v.z;
            Xs[(k + 3) * 65 + i] = v.w;
        }
        __syncthreads();
        const int ploc = tid & 63;
        const int j0 = tid >> 6;
        float acc[13];
#pragma unroll
        for (int m = 0; m < 13; ++m) {
            int jj = j0 * 13 + m;
            acc[m] = (jj < 50) ? b1[jj] : 0.f;
        }
        for (int k4 = 0; k4 < 32; ++k4) {
            const int k = 4 * k4;
            float x0 = Xs[(k + 0) * 65 + ploc];
            float x1 = Xs[(k + 1) * 65 + ploc];
            float x2 = Xs[(k + 2) * 65 + ploc];
            float x3 = Xs[(k + 3) * 65 + ploc];
#pragma unroll
            for (int m = 0; m < 13; ++m) {
                int jj = j0 * 13 + m;
                if (jj < 50) {
                    float4 wv = *(const float4*)&W1T[jj * 128 + k];
                    acc[m] += x0 * wv.x + x1 * wv.y + x2 * wv.z + x3 * wv.w;
                }
            }
        }
        int p = p0 + ploc;
        if (p < PP) {
#pragma unroll
            for (int m = 0; m < 13; ++m) {
                int jj = j0 * 13 + m;
                if (jj < 50) XcT[jj * PP + p] = acc[m];
            }
        }
        for (int idx = tid; idx < 6 * 64; idx += 256) {
            int r = 50 + (idx >> 6);
            int pp = p0 + (idx & 63);
            if (pp < PP) XcT[r * PP + pp] = 0.f;
        }
    }
}

// ---------------- K4: suffix-accumulate V[p,j] += a[s,p]*Gs[s,j]; emit per t-chunk -----
__global__ __launch_bounds__(256) void k4_main(const int* __restrict__ pro_id,
    const float* __restrict__ cos_X, const float* __restrict__ XcT,
    const float* __restrict__ G, const float* __restrict__ W2,
    const float* __restrict__ b2, float* __restrict__ out)
{
    __shared__ __align__(16) float Gs[TT * GROW];  // 22.4 KB
    __shared__ float w2s[NJ];
    __shared__ int spid[TT];
    const int b = blockIdx.z;
    const int p = blockIdx.y * 256 + threadIdx.x;
    const int ci = blockIdx.x;
    const int t0 = ci * 7;
    const int t1 = (t0 + 7 < TT) ? (t0 + 7) : TT;
    const bool valid = p < PP;
    const int pc = valid ? p : 0;
    const int tid = threadIdx.x;

    {
        const float4* Gg = (const float4*)(G + b * TT * GROW);
        float4* Gd = (float4*)Gs;
        for (int idx = tid; idx < TT * GROW / 4; idx += 256) Gd[idx] = Gg[idx];
        if (tid < TT) spid[tid] = pro_id[b * TT + tid];
        if (tid < NJ) w2s[tid] = (tid < 50) ? W2[tid] : 0.f;
    }

    float V[NJ];
#pragma unroll
    for (int jj = 0; jj < NJ; ++jj) V[jj] = XcT[jj * PP + pc];
    const float b2v = b2[0];
    __syncthreads();

    const float* cb = cos_X + pc;
    float a0 = cb[spid[99] * PP];
    float a1 = cb[spid[98] * PP];
    float a2 = cb[spid[97] * PP];
    float a3 = cb[spid[96] * PP];

    for (int s = TT - 1; s >= t0; --s) {
        float a = a0; a0 = a1; a1 = a2; a2 = a3;
        int sp = s - 4;
        if (sp < t0) sp = t0;
        a3 = cb[spid[sp] * PP];
        const float4* G4 = (const float4*)&Gs[s * GROW];
#pragma unroll
        for (int jv = 0; jv < 13; ++jv) {
            float4 gv = G4[jv];
            V[4 * jv + 0] += a * gv.x;
            V[4 * jv + 1] += a * gv.y;
            V[4 * jv + 2] += a * gv.z;
            V[4 * jv + 3] += a * gv.w;
        }
        if (s < t1) {
            float acc = b2v;
#pragma unroll
            for (int jv = 0; jv < 13; ++jv) {
                float4 wv = *(const float4*)&w2s[4 * jv];
                acc += wv.x * fmaxf(V[4 * jv + 0], 0.f)
                     + wv.y * fmaxf(V[4 * jv + 1], 0.f)
                     + wv.z * fmaxf(V[4 * jv + 2], 0.f)
                     + wv.w * fmaxf(V[4 * jv + 3], 0.f);
            }
            if (valid) out[(b * TT + s) * PP + p] = acc;
        }
    }
}

extern "C" void kernel_launch(void* const* d_in, const int* in_sizes, int n_in,
                              void* d_out, int out_size, void* d_ws, size_t ws_size,
                              hipStream_t stream)
{
    const int* pro_id  = (const int*)d_in[0];
    const int* label   = (const int*)d_in[1];
    const float* X     = (const float*)d_in[3];
    const float* cos_X = (const float*)d_in[4];
    // d_in[5] trimatrix: structurally tril(ones) — suffix-sum semantics hardcoded
    const float* onehot = (const float*)d_in[6];
    const float* lk    = (const float*)d_in[7];
    const float* lr    = (const float*)d_in[8];
    const float* lb    = (const float*)d_in[9];
    const float* W1    = (const float*)d_in[10];
    const float* b1    = (const float*)d_in[11];
    const float* W2    = (const float*)d_in[12];
    const float* b2    = (const float*)d_in[13];

    float* ws  = (float*)d_ws;
    float* xk  = ws;            // 204800
    float* XcT = ws + 204800;   // 56000
    float* G   = ws + 260800;   // 44800
    float* out = (float*)d_out;

    // mid uses 138 KiB dynamic LDS (>64 KiB default cap) — host-side, set once.
    static bool smem_attr_set = false;
    if (!smem_attr_set) {
        hipFuncSetAttribute((const void*)mid,
                            hipFuncAttributeMaxDynamicSharedMemorySize,
                            MID_SMEM_BYTES);
        smem_attr_set = true;
    }

    hipLaunchKernelGGL(k1_xk,  dim3(400),      dim3(256), 0, stream,
                       pro_id, label, X, onehot, lk, lb, xk);
    hipLaunchKernelGGL(mid,    dim3(24),       dim3(256), MID_SMEM_BYTES, stream,
                       xk, lr, W1, X, b1, G, XcT);
    hipLaunchKernelGGL(k4_main,dim3(15, 4, 8), dim3(256), 0, stream,
                       pro_id, cos_X, XcT, G, W2, b2, out);
}

// Round 7
// 206.739 us; speedup vs baseline: 1.1364x; 1.1364x over previous
//
#include <hip/hip_runtime.h>
#include <math.h>

#define BB 8
#define TT 100
#define PP 1000
#define NJ 52      // V regs per thread in k4 (50 real j, 2 pad)
#define GROW 56    // G row stride floats (224B, 16B aligned)

// mid static LDS (floats): xk_lds [100][256] | h_all [100][64] | w1s [64][52]
#define MID_XK   0
#define MID_HALL 25600
#define MID_W1S  32000
#define MID_SMEM_FLOATS 35328   // 141312 B static <= 160 KiB/CU

typedef _Float16 half2v __attribute__((ext_vector_type(2)));

// ws layout (floats):
//   xk : [800][256] at 0        (204800)
//   XcT: [56][1000] at 204800   (56000)
//   G  : [800][56]  at 260800   (44800)

// ---------------- K1: xk[bt][j] = bias[j] + sum_k xt[bt][k]*kern[k][j] -----------------
__global__ __launch_bounds__(256) void k1_xk(const int* __restrict__ pro_id,
    const int* __restrict__ label, const float* __restrict__ X,
    const float* __restrict__ onehot, const float* __restrict__ kern,
    const float* __restrict__ bias, float* __restrict__ xk)
{
    __shared__ __align__(16) float xt[2][256];
    const int j = threadIdx.x;
    const int r0 = blockIdx.x * 2;
#pragma unroll
    for (int r = 0; r < 2; ++r) {
        int pid = pro_id[r0 + r];
        int lab = label[r0 + r];
        xt[r][j] = X[pid * 128 + (j & 127)] * onehot[lab * 256 + j];
    }
    __syncthreads();
    float acc0 = bias[j], acc1 = acc0;
    float kc[8];
#pragma unroll
    for (int i = 0; i < 8; ++i) kc[i] = kern[i * 256 + j];
    for (int kg = 0; kg < 32; ++kg) {
        float kn[8];
        const int kgn = (kg < 31) ? kg + 1 : 31;
#pragma unroll
        for (int i = 0; i < 8; ++i) kn[i] = kern[(kgn * 8 + i) * 256 + j];
        const int k0 = kg * 8;
        float4 xa0 = *(const float4*)&xt[0][k0];
        float4 xa1 = *(const float4*)&xt[0][k0 + 4];
        float4 xb0 = *(const float4*)&xt[1][k0];
        float4 xb1 = *(const float4*)&xt[1][k0 + 4];
        acc0 += xa0.x * kc[0] + xa0.y * kc[1] + xa0.z * kc[2] + xa0.w * kc[3]
              + xa1.x * kc[4] + xa1.y * kc[5] + xa1.z * kc[6] + xa1.w * kc[7];
        acc1 += xb0.x * kc[0] + xb0.y * kc[1] + xb0.z * kc[2] + xb0.w * kc[3]
              + xb1.x * kc[4] + xb1.y * kc[5] + xb1.z * kc[6] + xb1.w * kc[7];
#pragma unroll
        for (int i = 0; i < 8; ++i) kc[i] = kn[i];
    }
    xk[(r0 + 0) * 256 + j] = acc0;
    xk[(r0 + 1) * 256 + j] = acc1;
}

// ---------------- MID: blocks 0..7 = LSTM (1 batch), blocks 8..23 = XcT (k3) -----------
// LSTM v12: xk-LDS experiment, STATIC LDS.
// R3/R5/R6 post-mortem: dynamic (extern) LDS was the poison, not barriers.
// The AMDGPU backend budgets VGPRs from STATIC LDS occupancy; extern LDS is
// invisible -> allocator targets ~5 waves/EU -> 88 VGPR cap -> rp[4][32]
// (128 regs) rematerialized from global inside the loop (+35-40us). Static
// 141.3KB LDS -> backend sees 1 block/CU -> full 512-VGPR budget -> rp stays.
// Structure identical to R6: uniform stage -> uniform barrier ->
// if(tid<64){rp setup; recurrence} -> uniform barrier -> G tail.
__global__ __launch_bounds__(256, 1) void mid(const float* __restrict__ xk,
    const float* __restrict__ rec, const float* __restrict__ W1,
    const float* __restrict__ X, const float* __restrict__ b1,
    float* __restrict__ G, float* __restrict__ XcT)
{
    __shared__ __align__(16) float smem[MID_SMEM_FLOATS];  // 141.3 KB static
    const int tid = threadIdx.x;

    if (blockIdx.x < 8) {
        float* xk_lds = smem + MID_XK;     // [100][256] f32 = 102400 B
        float* h_all  = smem + MID_HALL;   // [100][64] f32 (for G tail)
        float* w1s    = smem + MID_W1S;    // [64][52]
        const int b = blockIdx.x;

        // ---- ALL threads: stage xk tile (100KB) + w1s, uniform barrier ----
        {
            const float4* xkg = (const float4*)(xk + b * TT * 256);
            float4* xkd = (float4*)xk_lds;
            for (int idx = tid; idx < TT * 64; idx += 256)
                xkd[idx] = xkg[idx];
            for (int idx = tid; idx < 3200; idx += 256) {
                int u2 = idx / 50, jj = idx - u2 * 50;
                w1s[u2 * 52 + jj] = W1[idx];
            }
        }
        __syncthreads();   // uniform: xk_lds + w1s ready

        if (tid < 64) {    // wave 0: rp setup + recurrence, NO barrier in scope
            const int u = tid;
            // rec as f16 dot2 pairs: rp[g][m] = (rec[2m][g*64+u], rec[2m+1][g*64+u])
            half2v rp[4][32];
#pragma unroll
            for (int m = 0; m < 32; ++m) {
#pragma unroll
                for (int g2 = 0; g2 < 4; ++g2) {
                    float r0 = rec[(2 * m) * 256 + g2 * 64 + u];
                    float r1 = rec[(2 * m + 1) * 256 + g2 * 64 + u];
                    half2v pv; pv.x = (_Float16)r0; pv.y = (_Float16)r1;
                    rp[g2][m] = pv;
                }
            }

            float xi = xk_lds[u],       xf = xk_lds[64 + u],
                  xg = xk_lds[128 + u], xo = xk_lds[192 + u];
            float c = 0.f;
            half2v prb; prb.x = (_Float16)0.f; prb.y = (_Float16)0.f;  // h(-1)=0

            for (int t = 0; t < TT; ++t) {
                float zi = xi, zf = xf, zg = xg, zo = xo;
                // prefetch next step's xk row from LDS (hidden under the dots)
                const float* xp = xk_lds + ((t + 1 < TT) ? (t + 1) : (TT - 1)) * 256;
                xi = xp[u];       xf = xp[64 + u];
                xg = xp[128 + u]; xo = xp[192 + u];
                const int prbi = __builtin_bit_cast(int, prb);
#pragma unroll
                for (int m = 0; m < 32; ++m) {
                    half2v pm = __builtin_bit_cast(half2v,
                        __builtin_amdgcn_readlane(prbi, 2 * m));
                    zi = __builtin_amdgcn_fdot2(pm, rp[0][m], zi, false);
                    zf = __builtin_amdgcn_fdot2(pm, rp[1][m], zf, false);
                    zg = __builtin_amdgcn_fdot2(pm, rp[2][m], zg, false);
                    zo = __builtin_amdgcn_fdot2(pm, rp[3][m], zo, false);
                }
                float gi = __builtin_amdgcn_rcpf(1.f + __expf(-zi));
                float gf = __builtin_amdgcn_rcpf(1.f + __expf(-zf));
                float gg = 2.f * __builtin_amdgcn_rcpf(1.f + __expf(-2.f * zg)) - 1.f;
                float go = __builtin_amdgcn_rcpf(1.f + __expf(-zo));
                c = gf * c + gi * gg;
                float h = go * (2.f * __builtin_amdgcn_rcpf(1.f + __expf(-2.f * c)) - 1.f);
                h_all[t * 64 + u] = h;   // f32 history, off critical path
                // (h[u], h[u^1]) via DPP quad_perm [1,0,3,2]
                int hsw = __builtin_amdgcn_update_dpp(0,
                    __builtin_bit_cast(int, h), 0xB1, 0xF, 0xF, true);
                half2v pn;
                pn.x = (_Float16)h;
                pn.y = (_Float16)__builtin_bit_cast(float, hsw);
                prb = pn;   // even lane 2m holds (h[2m], h[2m+1])
            }
        }
        __syncthreads();   // uniform: h_all visible to all 4 waves

        // ---- G tail (all 256 threads): G[b*100+row][j] = h(row) . W1[:,j] ----
        const int brow0 = b * TT;
        for (int idx = tid; idx < TT * 13; idx += 256) {
            int row = idx / 13;
            int m = idx - row * 13;
            int j = 4 * m;
            const float* hrow = &h_all[row * 64];
            float ax = 0.f, ay = 0.f, az = 0.f, aw = 0.f;
#pragma unroll
            for (int u4 = 0; u4 < 16; ++u4) {
                float4 hv  = *(const float4*)&hrow[4 * u4];
                float4 w0  = *(const float4*)&w1s[(4 * u4 + 0) * 52 + j];
                float4 w1v = *(const float4*)&w1s[(4 * u4 + 1) * 52 + j];
                float4 w2  = *(const float4*)&w1s[(4 * u4 + 2) * 52 + j];
                float4 w3  = *(const float4*)&w1s[(4 * u4 + 3) * 52 + j];
                ax += hv.x * w0.x + hv.y * w1v.x + hv.z * w2.x + hv.w * w3.x;
                ay += hv.x * w0.y + hv.y * w1v.y + hv.z * w2.y + hv.w * w3.y;
                az += hv.x * w0.z + hv.y * w1v.z + hv.z * w2.z + hv.w * w3.z;
                aw += hv.x * w0.w + hv.y * w1v.w + hv.z * w2.w + hv.w * w3.w;
            }
            if (m == 12) { az = 0.f; aw = 0.f; }   // cols 50,51 = 0
            *(float4*)&G[(brow0 + row) * GROW + j] = make_float4(ax, ay, az, aw);
        }
    } else {
        // ---- k3: XcT[j][p] = b1[j] + sum_k X[p][k]*W1[64+k][j] ----
        float* Xs  = smem;          // [128][65]
        float* W1T = smem + 8320;   // [50][128]
        const int p0 = (blockIdx.x - 8) * 64;
        for (int idx = tid; idx < 6400; idx += 256) {
            int k = idx & 127, jj = idx >> 7;
            W1T[jj * 128 + k] = W1[(64 + k) * 50 + jj];
        }
#pragma unroll
        for (int r = 0; r < 8; ++r) {
            int flat = (tid + 256 * r) * 4;
            int i = flat >> 7;
            int k = flat & 127;
            int p = p0 + i;
            float4 v = make_float4(0.f, 0.f, 0.f, 0.f);
            if (p < PP) v = *(const float4*)&X[p * 128 + k];
            Xs[(k + 0) * 65 + i] = v.x;
            Xs[(k + 1) * 65 + i] = v.y;
            Xs[(k + 2) * 65 + i] = v.z;
            Xs[(k + 3) * 65 + i] = v.w;
        }
        __syncthreads();
        const int ploc = tid & 63;
        const int j0 = tid >> 6;
        float acc[13];
#pragma unroll
        for (int m = 0; m < 13; ++m) {
            int jj = j0 * 13 + m;
            acc[m] = (jj < 50) ? b1[jj] : 0.f;
        }
        for (int k4 = 0; k4 < 32; ++k4) {
            const int k = 4 * k4;
            float x0 = Xs[(k + 0) * 65 + ploc];
            float x1 = Xs[(k + 1) * 65 + ploc];
            float x2 = Xs[(k + 2) * 65 + ploc];
            float x3 = Xs[(k + 3) * 65 + ploc];
#pragma unroll
            for (int m = 0; m < 13; ++m) {
                int jj = j0 * 13 + m;
                if (jj < 50) {
                    float4 wv = *(const float4*)&W1T[jj * 128 + k];
                    acc[m] += x0 * wv.x + x1 * wv.y + x2 * wv.z + x3 * wv.w;
                }
            }
        }
        int p = p0 + ploc;
        if (p < PP) {
#pragma unroll
            for (int m = 0; m < 13; ++m) {
                int jj = j0 * 13 + m;
                if (jj < 50) XcT[jj * PP + p] = acc[m];
            }
        }
        for (int idx = tid; idx < 6 * 64; idx += 256) {
            int r = 50 + (idx >> 6);
            int pp = p0 + (idx & 63);
            if (pp < PP) XcT[r * PP + pp] = 0.f;
        }
    }
}

// ---------------- K4: suffix-accumulate V[p,j] += a[s,p]*Gs[s,j]; emit per t-chunk -----
__global__ __launch_bounds__(256) void k4_main(const int* __restrict__ pro_id,
    const float* __restrict__ cos_X, const float* __restrict__ XcT,
    const float* __restrict__ G, const float* __restrict__ W2,
    const float* __restrict__ b2, float* __restrict__ out)
{
    __shared__ __align__(16) float Gs[TT * GROW];  // 22.4 KB
    __shared__ float w2s[NJ];
    __shared__ int spid[TT];
    const int b = blockIdx.z;
    const int p = blockIdx.y * 256 + threadIdx.x;
    const int ci = blockIdx.x;
    const int t0 = ci * 7;
    const int t1 = (t0 + 7 < TT) ? (t0 + 7) : TT;
    const bool valid = p < PP;
    const int pc = valid ? p : 0;
    const int tid = threadIdx.x;

    {
        const float4* Gg = (const float4*)(G + b * TT * GROW);
        float4* Gd = (float4*)Gs;
        for (int idx = tid; idx < TT * GROW / 4; idx += 256) Gd[idx] = Gg[idx];
        if (tid < TT) spid[tid] = pro_id[b * TT + tid];
        if (tid < NJ) w2s[tid] = (tid < 50) ? W2[tid] : 0.f;
    }

    float V[NJ];
#pragma unroll
    for (int jj = 0; jj < NJ; ++jj) V[jj] = XcT[jj * PP + pc];
    const float b2v = b2[0];
    __syncthreads();

    const float* cb = cos_X + pc;
    float a0 = cb[spid[99] * PP];
    float a1 = cb[spid[98] * PP];
    float a2 = cb[spid[97] * PP];
    float a3 = cb[spid[96] * PP];

    for (int s = TT - 1; s >= t0; --s) {
        float a = a0; a0 = a1; a1 = a2; a2 = a3;
        int sp = s - 4;
        if (sp < t0) sp = t0;
        a3 = cb[spid[sp] * PP];
        const float4* G4 = (const float4*)&Gs[s * GROW];
#pragma unroll
        for (int jv = 0; jv < 13; ++jv) {
            float4 gv = G4[jv];
            V[4 * jv + 0] += a * gv.x;
            V[4 * jv + 1] += a * gv.y;
            V[4 * jv + 2] += a * gv.z;
            V[4 * jv + 3] += a * gv.w;
        }
        if (s < t1) {
            float acc = b2v;
#pragma unroll
            for (int jv = 0; jv < 13; ++jv) {
                float4 wv = *(const float4*)&w2s[4 * jv];
                acc += wv.x * fmaxf(V[4 * jv + 0], 0.f)
                     + wv.y * fmaxf(V[4 * jv + 1], 0.f)
                     + wv.z * fmaxf(V[4 * jv + 2], 0.f)
                     + wv.w * fmaxf(V[4 * jv + 3], 0.f);
            }
            if (valid) out[(b * TT + s) * PP + p] = acc;
        }
    }
}

extern "C" void kernel_launch(void* const* d_in, const int* in_sizes, int n_in,
                              void* d_out, int out_size, void* d_ws, size_t ws_size,
                              hipStream_t stream)
{
    const int* pro_id  = (const int*)d_in[0];
    const int* label   = (const int*)d_in[1];
    const float* X     = (const float*)d_in[3];
    const float* cos_X = (const float*)d_in[4];
    // d_in[5] trimatrix: structurally tril(ones) — suffix-sum semantics hardcoded
    const float* onehot = (const float*)d_in[6];
    const float* lk    = (const float*)d_in[7];
    const float* lr    = (const float*)d_in[8];
    const float* lb    = (const float*)d_in[9];
    const float* W1    = (const float*)d_in[10];
    const float* b1    = (const float*)d_in[11];
    const float* W2    = (const float*)d_in[12];
    const float* b2    = (const float*)d_in[13];

    float* ws  = (float*)d_ws;
    float* xk  = ws;            // 204800
    float* XcT = ws + 204800;   // 56000
    float* G   = ws + 260800;   // 44800
    float* out = (float*)d_out;

    hipLaunchKernelGGL(k1_xk,  dim3(400),      dim3(256), 0, stream,
                       pro_id, label, X, onehot, lk, lb, xk);
    hipLaunchKernelGGL(mid,    dim3(24),       dim3(256), 0, stream,
                       xk, lr, W1, X, b1, G, XcT);
    hipLaunchKernelGGL(k4_main,dim3(15, 4, 8), dim3(256), 0, stream,
                       pro_id, cos_X, XcT, G, W2, b2, out);
}